// Round 5
// baseline (2644.255 us; speedup 1.0000x reference)
//
#include <hip/hip_runtime.h>
#include <hip/hip_bf16.h>
#include <hip/hip_fp16.h>

#define DEVI __device__ __forceinline__

typedef _Float16 f16x8 __attribute__((ext_vector_type(8)));
typedef float f32x4 __attribute__((ext_vector_type(4)));
typedef float f32x16 __attribute__((ext_vector_type(16)));

static constexpr int M = 32768;   // batch
static constexpr int N = 1024;    // H21
static constexpr int K = 2048;    // H1
static constexpr int BM = 256, BN = 256, BK = 32;
static constexpr int NT = K / BK;            // 64 k-tiles
static constexpr int NSTRIP = (N / BN) * 4;  // 16 partial strips

// ---- ws layout ----
static constexpr size_t WS_H    = 0;                       // f16 [M][K]
static constexpr size_t WS_W21T = 134217728;               // f16 [N][K]
static constexpr size_t WS_PART = 134217728 + 4194304;     // f32 [16][M][2]

using lds_vp = __attribute__((address_space(3))) void*;
using gbl_vp = const __attribute__((address_space(1))) void*;

DEVI void async_ld16(const void* g, void* l) {
  __builtin_amdgcn_global_load_lds((gbl_vp)(size_t)g,
                                   (lds_vp)(uint32_t)(size_t)l,
                                   16, 0, 0);
}

// ---------- prep: W21 [K][N] fp32 -> W21^T [N][K] f16 ----------
__global__ __launch_bounds__(256)
void w21cvt_kernel(const float* __restrict__ W21, _Float16* __restrict__ w21t) {
  __shared__ float sT[64][65];
  const int tid = threadIdx.x;
  const int k0 = blockIdx.x * 64;
  const int n0 = blockIdx.y * 64;
  const int row = tid >> 2;
#pragma unroll
  for (int q = 0; q < 4; ++q) {
    int c = (tid & 3) * 4 + q * 16;
    float4 v = *(const float4*)(W21 + (size_t)(k0 + row) * 1024 + n0 + c);
    sT[row][c + 0] = v.x; sT[row][c + 1] = v.y;
    sT[row][c + 2] = v.z; sT[row][c + 3] = v.w;
  }
  __syncthreads();
  const int n  = tid >> 2;
  const int kc = (tid & 3) * 16;
  union { _Float16 h[16]; float4 f4[2]; } u;
#pragma unroll
  for (int e = 0; e < 16; ++e) u.h[e] = (_Float16)sT[kc + e][n];
  float4* dst = (float4*)(w21t + (size_t)(n0 + n) * 2048 + k0 + kc);
  dst[0] = u.f4[0]; dst[1] = u.f4[1];
}

// ---------- gemm1: h = relu(x@W1 + b1), fp32 math, f16 out ----------
__global__ __launch_bounds__(256)
void gemm1_kernel(const float* __restrict__ x, const float* __restrict__ W1,
                  const float* __restrict__ b1, _Float16* __restrict__ hout) {
  __shared__ float sx[64 * 8];
  const int tid = threadIdx.x;
  const int r0 = blockIdx.x * 64;
  if (tid < 128) {
    *(float4*)&sx[tid * 4] = *(const float4*)(x + (size_t)r0 * 8 + tid * 4);
  }
  float w1r[8][8];
#pragma unroll
  for (int j = 0; j < 8; ++j) {
    *(float4*)&w1r[j][0] = *(const float4*)(W1 + j * 2048 + tid * 8);
    *(float4*)&w1r[j][4] = *(const float4*)(W1 + j * 2048 + tid * 8 + 4);
  }
  float bb[8];
  *(float4*)&bb[0] = *(const float4*)(b1 + tid * 8);
  *(float4*)&bb[4] = *(const float4*)(b1 + tid * 8 + 4);
  __syncthreads();
  for (int r = 0; r < 64; ++r) {
    float xv[8];
    *(float4*)&xv[0] = *(float4*)&sx[r * 8];
    *(float4*)&xv[4] = *(float4*)&sx[r * 8 + 4];
    float acc[8];
#pragma unroll
    for (int c = 0; c < 8; ++c) acc[c] = bb[c];
#pragma unroll
    for (int j = 0; j < 8; ++j)
#pragma unroll
      for (int c = 0; c < 8; ++c) acc[c] = fmaf(xv[j], w1r[j][c], acc[c]);
    union { f16x8 v; float4 f4; } u;
#pragma unroll
    for (int c = 0; c < 8; ++c) u.v[c] = (_Float16)fmaxf(acc[c], 0.f);
    *(float4*)(hout + (size_t)(r0 + r) * 2048 + tid * 8) = u.f4;
  }
}

// ---------- gemm2: 256x256, BK=32, 2 blocks/CU, 32x32x16 MFMA, counted vmcnt ----------
// LDS 64 KiB: buf p in {0,1}: [A 16K][B 16K]. Row = 64 B = 4 chunks of 16B,
// slot = (chunk + ((row&15)>>1)) & 3  (R3-proven rotation swizzle).
__global__ __launch_bounds__(512, 4)
void gemm2_kernel(const _Float16* __restrict__ h, const _Float16* __restrict__ w21t,
                  const float* __restrict__ b21, const float* __restrict__ w31,
                  float* __restrict__ part) {
  __shared__ __align__(16) char smem[65536];

  const int tid  = threadIdx.x;
  const int lane = tid & 63;
  const int w    = tid >> 6;      // 0..7
  const int wr   = w >> 2;        // 0..1 -> 128 rows
  const int wc   = w & 3;         // 0..3 -> 64 cols

  const int lin  = blockIdx.x;
  const int swz  = (lin & 7) * 64 + (lin >> 3);
  const int nblk = swz & 3;
  const int mblk = swz >> 2;
  const int r0 = mblk * BM;
  const int n0 = nblk * BN;

  f32x16 acc[4][2] = {};

  // staging: dest cell idx = i*512 + tid -> row = i*128 + (tid>>2), slot = tid&3.
  // source chunk c = (slot - ((row&15)>>1)) & 3 = ((tid&3) - (tid>>3)) & 3
  const int cA = ((tid & 3) - (tid >> 3)) & 3;
  const _Float16* pA = h    + (size_t)(r0 + (tid >> 2)) * K + cA * 8;
  const _Float16* pB = w21t + (size_t)(n0 + (tid >> 2)) * K + cA * 8;

  auto stageAB = [&](int t) {
    char* dA = smem + (t & 1) * 32768 + tid * 16;
    const _Float16* gAt = pA + t * BK;
    async_ld16(gAt,                   dA);
    async_ld16(gAt + (size_t)128 * K, dA + 8192);
    char* dB = dA + 16384;
    const _Float16* gBt = pB + t * BK;
    async_ld16(gBt,                   dB);
    async_ld16(gBt + (size_t)128 * K, dB + 8192);
  };

  // ---- frag read addresses (swizzled) ----
  // A(m, ks): row = wr*128 + m*32 + (lane&31); chunk = ks*2 + (lane>>5)
  const int lrow  = lane & 31;
  const int khalf = lane >> 5;
  const int l15h  = (lane & 15) >> 1;
  const int abase = (wr * 128 + lrow) * 64;
  const int bbase = 16384 + (wc * 64 + lrow) * 64;
  int slotk[2];
#pragma unroll
  for (int ks = 0; ks < 2; ++ks)
    slotk[ks] = ((ks * 2 + khalf + l15h) & 3) * 16;

#define SB __builtin_amdgcn_sched_barrier(0)
#define BAR __builtin_amdgcn_s_barrier()
#define LGKM0 asm volatile("s_waitcnt lgkmcnt(0)" ::: "memory")

  // ---- prologue: stage tiles 0,1 ----
  stageAB(0);
  stageAB(1);
  asm volatile("s_waitcnt vmcnt(4)" ::: "memory");   // tile 0 resident
  BAR;

  for (int t = 0; t < NT; ++t) {
    const char* base = smem + (t & 1) * 32768;
    f16x8 aF[4], bF[2];

    // ---- ph0: read ks=0 frags; MFMA ks0 ----
#pragma unroll
    for (int m = 0; m < 4; ++m) aF[m] = *(const f16x8*)(base + abase + m * 2048 + slotk[0]);
#pragma unroll
    for (int n = 0; n < 2; ++n) bF[n] = *(const f16x8*)(base + bbase + n * 2048 + slotk[0]);
    SB;
    BAR; LGKM0; SB;
    __builtin_amdgcn_s_setprio(1);
#pragma unroll
    for (int m = 0; m < 4; ++m)
#pragma unroll
      for (int n = 0; n < 2; ++n)
        acc[m][n] = __builtin_amdgcn_mfma_f32_32x32x16_f16(aF[m], bF[n], acc[m][n], 0, 0, 0);
    __builtin_amdgcn_s_setprio(0); SB;
    BAR;

    // ---- ph1: read ks=1 frags; MFMA ks1; stage t+2; counted vmcnt ----
#pragma unroll
    for (int m = 0; m < 4; ++m) aF[m] = *(const f16x8*)(base + abase + m * 2048 + slotk[1]);
#pragma unroll
    for (int n = 0; n < 2; ++n) bF[n] = *(const f16x8*)(base + bbase + n * 2048 + slotk[1]);
    SB;
    BAR; LGKM0; SB;
    __builtin_amdgcn_s_setprio(1);
#pragma unroll
    for (int m = 0; m < 4; ++m)
#pragma unroll
      for (int n = 0; n < 2; ++n)
        acc[m][n] = __builtin_amdgcn_mfma_f32_32x32x16_f16(aF[m], bF[n], acc[m][n], 0, 0, 0);
    __builtin_amdgcn_s_setprio(0); SB;
    // safe: all waves' reads of buf[t&1] retired before their MFMA above
    if (t + 2 < NT) stageAB(t + 2);
    if (t < NT - 2) asm volatile("s_waitcnt vmcnt(4)" ::: "memory");
    else            asm volatile("s_waitcnt vmcnt(0)" ::: "memory");
    BAR;
  }

  // ---- epilogue: a = relu(acc + b21); s = a @ W31; 4-pass LDS transpose-reduce ----
  float bb[2], w0v[2], w1v[2];
#pragma unroll
  for (int n = 0; n < 2; ++n) {
    int cg = n0 + wc * 64 + n * 32 + lrow;
    bb[n]  = b21[cg];
    w0v[n] = w31[cg * 2 + 0];
    w1v[n] = w31[cg * 2 + 1];
  }
  float* red = (float*)smem;
  for (int m = 0; m < 4; ++m) {
    __syncthreads();
    // write: red[w][rloc 0..31][col 0..31] float2  (64 KB)
#pragma unroll
    for (int r = 0; r < 16; ++r) {
      float a0 = fmaxf(acc[m][0][r] + bb[0], 0.f);
      float a1 = fmaxf(acc[m][1][r] + bb[1], 0.f);
      float s0 = fmaf(a0, w0v[0], a1 * w0v[1]);
      float s1 = fmaf(a0, w1v[0], a1 * w1v[1]);
      int rloc = (r & 3) + 8 * (r >> 2) + 4 * khalf;
      int idx = w * 2048 + rloc * 64 + lrow * 2;
      red[idx]     = s0;
      red[idx + 1] = s1;
    }
    __syncthreads();
    if (tid < 256) {
      const int w2 = tid >> 5, rloc = tid & 31;
      const float* src = red + w2 * 2048 + rloc * 64;
      float a0 = 0.f, a1 = 0.f;
#pragma unroll
      for (int k = 0; k < 16; ++k) {
        int kk = (k + (tid & 15)) & 15;
        float4 v = *(const float4*)(src + kk * 4);
        a0 += v.x + v.z;
        a1 += v.y + v.w;
      }
      int gr = r0 + (w2 >> 2) * 128 + m * 32 + rloc;
      int strip = nblk * 4 + (w2 & 3);
      float2 o; o.x = a0; o.y = a1;
      *(float2*)(part + ((size_t)strip * M + gr) * 2) = o;
    }
  }
#undef SB
#undef BAR
#undef LGKM0
}

// ---------- final: sum strips, add b31, QP clip, de/normalize ----------
__global__ __launch_bounds__(256)
void final_kernel(const float* __restrict__ part, const float* __restrict__ b31,
                  const float* __restrict__ om, const float* __restrict__ os,
                  const float* __restrict__ s0p, const float* __restrict__ s1p,
                  const float* __restrict__ s2p, const float* __restrict__ s3p,
                  float* __restrict__ out) {
  const int r = blockIdx.x * blockDim.x + threadIdx.x;
  float a0 = b31[0], a1 = b31[1];
#pragma unroll
  for (int s = 0; s < NSTRIP; ++s) {
    float2 v = *(const float2*)(part + ((size_t)s * M + r) * 2);
    a0 += v.x; a1 += v.y;
  }
  const float om0 = om[0], om1 = om[1], os0 = os[0], os1 = os[1];
  const float xa0 = a0 * os0 + om0;
  const float xa1 = a1 * os1 + om1;
  const float up0 = 1.0f + s2p[0];
  const float up1 = 1.0f + s0p[0];
  const float lo0 = -(1.0f + s3p[0]);
  const float lo1 = -(1.0f + s1p[0]);
  const float u0 = fminf(fmaxf(-xa0, lo0), up0);
  const float u1 = fminf(fmaxf(-xa1, lo1), up1);
  float2 o; o.x = (u0 - om0) / os0; o.y = (u1 - om1) / os1;
  *(float2*)(out + (size_t)r * 2) = o;
}

extern "C" void kernel_launch(void* const* d_in, const int* in_sizes, int n_in,
                              void* d_out, int out_size, void* d_ws, size_t ws_size,
                              hipStream_t stream) {
  const float* x    = (const float*)d_in[0];
  const float* W1   = (const float*)d_in[1];
  const float* b1   = (const float*)d_in[2];
  const float* W21  = (const float*)d_in[3];
  const float* b21  = (const float*)d_in[4];
  const float* W31  = (const float*)d_in[5];
  const float* b31  = (const float*)d_in[6];
  const float* omean = (const float*)d_in[13];
  const float* ostd  = (const float*)d_in[14];
  const float* s0 = (const float*)d_in[15];
  const float* s1 = (const float*)d_in[16];
  const float* s2 = (const float*)d_in[17];
  const float* s3 = (const float*)d_in[18];
  float* out = (float*)d_out;

  char* ws = (char*)d_ws;
  _Float16* hbuf = (_Float16*)(ws + WS_H);
  _Float16* w21t = (_Float16*)(ws + WS_W21T);
  float*    part = (float*)(ws + WS_PART);

  w21cvt_kernel<<<dim3(32, 16), dim3(256), 0, stream>>>(W21, w21t);
  gemm1_kernel<<<dim3(512), dim3(256), 0, stream>>>(x, W1, b1, hbuf);
  gemm2_kernel<<<dim3((M / BM) * (N / BN)), dim3(512), 0, stream>>>(hbuf, w21t, b21, W31, part);
  final_kernel<<<dim3(M / 256), dim3(256), 0, stream>>>(part, b31, omean, ostd,
                                                        s0, s1, s2, s3, out);
}

// Round 6
// 189.293 us; speedup vs baseline: 13.9691x; 13.9691x over previous
//
#include <hip/hip_runtime.h>
#include <hip/hip_bf16.h>
#include <hip/hip_fp16.h>

#define DEVI __device__ __forceinline__

typedef _Float16 f16x8 __attribute__((ext_vector_type(8)));
typedef float f32x16 __attribute__((ext_vector_type(16)));

static constexpr int M = 32768;   // batch
static constexpr int N = 1024;    // H21
static constexpr int K = 2048;    // H1
static constexpr int BM = 128, BN = 256, BK = 32;
static constexpr int NT = K / BK;            // 64 k-tiles
static constexpr int NSTRIP = (N / BN) * 4;  // 16 partial strips
static constexpr int BUFB = 24576;           // bytes per LDS buffer (A 8K + B 16K)

// ---- ws layout ----
static constexpr size_t WS_H    = 0;                       // f16 [M][K]
static constexpr size_t WS_W21T = 134217728;               // f16 [N][K]
static constexpr size_t WS_PART = 134217728 + 4194304;     // f32 [16][M][2]

using lds_vp = __attribute__((address_space(3))) void*;
using gbl_vp = const __attribute__((address_space(1))) void*;

DEVI void async_ld16(const void* g, void* l) {
  __builtin_amdgcn_global_load_lds((gbl_vp)(size_t)g,
                                   (lds_vp)(uint32_t)(size_t)l,
                                   16, 0, 0);
}

// ---------- prep: W21 [K][N] fp32 -> W21^T [N][K] f16 ----------
__global__ __launch_bounds__(256)
void w21cvt_kernel(const float* __restrict__ W21, _Float16* __restrict__ w21t) {
  __shared__ float sT[64][65];
  const int tid = threadIdx.x;
  const int k0 = blockIdx.x * 64;
  const int n0 = blockIdx.y * 64;
  const int row = tid >> 2;
#pragma unroll
  for (int q = 0; q < 4; ++q) {
    int c = (tid & 3) * 4 + q * 16;
    float4 v = *(const float4*)(W21 + (size_t)(k0 + row) * 1024 + n0 + c);
    sT[row][c + 0] = v.x; sT[row][c + 1] = v.y;
    sT[row][c + 2] = v.z; sT[row][c + 3] = v.w;
  }
  __syncthreads();
  const int n  = tid >> 2;
  const int kc = (tid & 3) * 16;
  union { _Float16 h[16]; float4 f4[2]; } u;
#pragma unroll
  for (int e = 0; e < 16; ++e) u.h[e] = (_Float16)sT[kc + e][n];
  float4* dst = (float4*)(w21t + (size_t)(n0 + n) * 2048 + k0 + kc);
  dst[0] = u.f4[0]; dst[1] = u.f4[1];
}

// ---------- gemm1: h = relu(x@W1 + b1), fp32 math, f16 out ----------
__global__ __launch_bounds__(256)
void gemm1_kernel(const float* __restrict__ x, const float* __restrict__ W1,
                  const float* __restrict__ b1, _Float16* __restrict__ hout) {
  __shared__ float sx[64 * 8];
  const int tid = threadIdx.x;
  const int r0 = blockIdx.x * 64;
  if (tid < 128) {
    *(float4*)&sx[tid * 4] = *(const float4*)(x + (size_t)r0 * 8 + tid * 4);
  }
  float w1r[8][8];
#pragma unroll
  for (int j = 0; j < 8; ++j) {
    *(float4*)&w1r[j][0] = *(const float4*)(W1 + j * 2048 + tid * 8);
    *(float4*)&w1r[j][4] = *(const float4*)(W1 + j * 2048 + tid * 8 + 4);
  }
  float bb[8];
  *(float4*)&bb[0] = *(const float4*)(b1 + tid * 8);
  *(float4*)&bb[4] = *(const float4*)(b1 + tid * 8 + 4);
  __syncthreads();
  for (int r = 0; r < 64; ++r) {
    float xv[8];
    *(float4*)&xv[0] = *(float4*)&sx[r * 8];
    *(float4*)&xv[4] = *(float4*)&sx[r * 8 + 4];
    float acc[8];
#pragma unroll
    for (int c = 0; c < 8; ++c) acc[c] = bb[c];
#pragma unroll
    for (int j = 0; j < 8; ++j)
#pragma unroll
      for (int c = 0; c < 8; ++c) acc[c] = fmaf(xv[j], w1r[j][c], acc[c]);
    union { f16x8 v; float4 f4; } u;
#pragma unroll
    for (int c = 0; c < 8; ++c) u.v[c] = (_Float16)fmaxf(acc[c], 0.f);
    *(float4*)(hout + (size_t)(r0 + r) * 2048 + tid * 8) = u.f4;
  }
}

// ---------- gemm2: 128x256, BK=32, 3-buffer rotation, 1 barrier/tile, 2 blk/CU ----------
// LDS buffer: [A 128x32 f16 = 8K][B 256x32 f16 = 16K]; row = 4 slots x 16B,
// slot = (chunk + ((row>>1)&3)) & 3.
__global__ __launch_bounds__(512, 4)
void gemm2_kernel(const _Float16* __restrict__ h, const _Float16* __restrict__ w21t,
                  const float* __restrict__ b21, const float* __restrict__ w31,
                  float* __restrict__ part) {
  __shared__ __align__(16) char smem[3 * BUFB];   // 72 KiB

  const int tid  = threadIdx.x;
  const int lane = tid & 63;
  const int w    = tid >> 6;      // 0..7
  const int wr   = w >> 2;        // 0..1 -> 64 rows
  const int wc   = w & 3;         // 0..3 -> 64 cols

  const int lin  = blockIdx.x;                 // 1024 blocks, %8==0 -> bijective
  const int swz  = (lin & 7) * 128 + (lin >> 3);
  const int nblk = swz & 3;
  const int mblk = swz >> 2;
  const int r0 = mblk * BM;
  const int n0 = nblk * BN;

  f32x16 acc[2][2] = {};

  // ---- staging (pre-swizzled global source, linear LDS dest) ----
  // dest cell idx -> row = idx>>2 (mod region), slot = idx&3;
  // source chunk c = (slot - ((row>>1)&3)) & 3 = ((tid&3) - ((tid>>3)&3)) & 3
  const int cA = ((tid & 3) - ((tid >> 3) & 3)) & 3;
  const _Float16* pA = h    + (size_t)(r0 + (tid >> 2)) * K + cA * 8;
  const _Float16* pB = w21t + (size_t)(n0 + (tid >> 2)) * K + cA * 8;

  auto stageAB = [&](int t, int bufi) {
    char* dA = smem + bufi * BUFB + tid * 16;
    const _Float16* gAt = pA + t * BK;
    async_ld16(gAt, dA);                               // A: 128 rows, 1 issue
    char* dB = smem + bufi * BUFB + 8192 + tid * 16;
    const _Float16* gBt = pB + t * BK;
    async_ld16(gBt,                   dB);             // B rows 0-127
    async_ld16(gBt + (size_t)128 * K, dB + 8192);      // B rows 128-255
  };

  // ---- frag read offsets (swizzled); slot indep. of m/n because 32|rows ----
  const int lrow  = lane & 31;
  const int khalf = lane >> 5;
  const int rsw   = (lrow >> 1) & 3;
  int abyteK[2], bbyteK[2];
#pragma unroll
  for (int ks = 0; ks < 2; ++ks) {
    const int slot = ((ks * 2 + khalf) + rsw) & 3;
    abyteK[ks] = (wr * 64 + lrow) * 64 + slot * 16;            // + m*2048
    bbyteK[ks] = 8192 + (wc * 64 + lrow) * 64 + slot * 16;     // + n*2048
  }

#define SB __builtin_amdgcn_sched_barrier(0)
#define BAR __builtin_amdgcn_s_barrier()

  // ---- prologue: stage tiles 0,1 ----
  stageAB(0, 0);
  stageAB(1, 1);
  asm volatile("s_waitcnt vmcnt(3)" ::: "memory");   // tile 0 resident
  BAR;

  int bufi = 0;
  for (int t = 0; t < NT; ++t) {
    const char* base = smem + bufi * BUFB;
    f16x8 aF[2][2], bF[2][2];
#pragma unroll
    for (int ks = 0; ks < 2; ++ks) {
#pragma unroll
      for (int m = 0; m < 2; ++m)
        aF[ks][m] = *(const f16x8*)(base + abyteK[ks] + m * 2048);
#pragma unroll
      for (int n = 0; n < 2; ++n)
        bF[ks][n] = *(const f16x8*)(base + bbyteK[ks] + n * 2048);
    }
    __builtin_amdgcn_s_setprio(1);
#pragma unroll
    for (int ks = 0; ks < 2; ++ks)
#pragma unroll
      for (int m = 0; m < 2; ++m)
#pragma unroll
        for (int n = 0; n < 2; ++n)
          acc[m][n] = __builtin_amdgcn_mfma_f32_32x32x16_f16(
              aF[ks][m], bF[ks][n], acc[m][n], 0, 0, 0);
    __builtin_amdgcn_s_setprio(0);
    SB;
    // WAR-safe: buf[(t+2)%3] == buf[(t-1)%3]; all reads of t-1 retired before
    // each wave's t-1 tile-end barrier, which precedes this stage.
    const int nb = bufi + 2 >= 3 ? bufi - 1 : bufi + 2;
    if (t + 2 < NT) stageAB(t + 2, nb);
    if (t < NT - 2) asm volatile("s_waitcnt vmcnt(3)" ::: "memory");
    else            asm volatile("s_waitcnt vmcnt(0)" ::: "memory");
    BAR;
    bufi = bufi + 1 == 3 ? 0 : bufi + 1;
  }

  // ---- epilogue: a = relu(acc + b21); s = a @ W31; 2-pass LDS transpose-reduce ----
  float bb[2], w0v[2], w1v[2];
#pragma unroll
  for (int n = 0; n < 2; ++n) {
    int cg = n0 + wc * 64 + n * 32 + lrow;
    bb[n]  = b21[cg];
    w0v[n] = w31[cg * 2 + 0];
    w1v[n] = w31[cg * 2 + 1];
  }
  float* red = (float*)smem;      // 64 KB overlay per pass
#pragma unroll
  for (int mp = 0; mp < 2; ++mp) {
    __syncthreads();
#pragma unroll
    for (int r = 0; r < 16; ++r) {
      float a0 = fmaxf(acc[mp][0][r] + bb[0], 0.f);
      float a1 = fmaxf(acc[mp][1][r] + bb[1], 0.f);
      float s0 = fmaf(a0, w0v[0], a1 * w0v[1]);
      float s1 = fmaf(a0, w1v[0], a1 * w1v[1]);
      int rloc = (r & 3) + 8 * (r >> 2) + 4 * khalf;   // 0..31
      int idx = w * 2048 + rloc * 64 + lrow * 2;
      red[idx]     = s0;
      red[idx + 1] = s1;
    }
    __syncthreads();
    if (tid < 256) {
      const int w2 = tid >> 5, rloc = tid & 31;
      const float* src = red + w2 * 2048 + rloc * 64;
      float a0 = 0.f, a1 = 0.f;
#pragma unroll
      for (int k = 0; k < 16; ++k) {
        int kk = (k + (tid & 15)) & 15;
        float4 v = *(const float4*)(src + kk * 4);
        a0 += v.x + v.z;
        a1 += v.y + v.w;
      }
      int gr = r0 + (w2 >> 2) * 64 + mp * 32 + rloc;
      int strip = nblk * 4 + (w2 & 3);
      float2 o; o.x = a0; o.y = a1;
      *(float2*)(part + ((size_t)strip * M + gr) * 2) = o;
    }
  }
#undef SB
#undef BAR
}

// ---------- final: sum strips, add b31, QP clip, de/normalize ----------
__global__ __launch_bounds__(256)
void final_kernel(const float* __restrict__ part, const float* __restrict__ b31,
                  const float* __restrict__ om, const float* __restrict__ os,
                  const float* __restrict__ s0p, const float* __restrict__ s1p,
                  const float* __restrict__ s2p, const float* __restrict__ s3p,
                  float* __restrict__ out) {
  const int r = blockIdx.x * blockDim.x + threadIdx.x;
  float a0 = b31[0], a1 = b31[1];
#pragma unroll
  for (int s = 0; s < NSTRIP; ++s) {
    float2 v = *(const float2*)(part + ((size_t)s * M + r) * 2);
    a0 += v.x; a1 += v.y;
  }
  const float om0 = om[0], om1 = om[1], os0 = os[0], os1 = os[1];
  const float xa0 = a0 * os0 + om0;
  const float xa1 = a1 * os1 + om1;
  const float up0 = 1.0f + s2p[0];
  const float up1 = 1.0f + s0p[0];
  const float lo0 = -(1.0f + s3p[0]);
  const float lo1 = -(1.0f + s1p[0]);
  const float u0 = fminf(fmaxf(-xa0, lo0), up0);
  const float u1 = fminf(fmaxf(-xa1, lo1), up1);
  float2 o; o.x = (u0 - om0) / os0; o.y = (u1 - om1) / os1;
  *(float2*)(out + (size_t)r * 2) = o;
}

extern "C" void kernel_launch(void* const* d_in, const int* in_sizes, int n_in,
                              void* d_out, int out_size, void* d_ws, size_t ws_size,
                              hipStream_t stream) {
  const float* x    = (const float*)d_in[0];
  const float* W1   = (const float*)d_in[1];
  const float* b1   = (const float*)d_in[2];
  const float* W21  = (const float*)d_in[3];
  const float* b21  = (const float*)d_in[4];
  const float* W31  = (const float*)d_in[5];
  const float* b31  = (const float*)d_in[6];
  const float* omean = (const float*)d_in[13];
  const float* ostd  = (const float*)d_in[14];
  const float* s0 = (const float*)d_in[15];
  const float* s1 = (const float*)d_in[16];
  const float* s2 = (const float*)d_in[17];
  const float* s3 = (const float*)d_in[18];
  float* out = (float*)d_out;

  char* ws = (char*)d_ws;
  _Float16* hbuf = (_Float16*)(ws + WS_H);
  _Float16* w21t = (_Float16*)(ws + WS_W21T);
  float*    part = (float*)(ws + WS_PART);

  w21cvt_kernel<<<dim3(32, 16), dim3(256), 0, stream>>>(W21, w21t);
  gemm1_kernel<<<dim3(512), dim3(256), 0, stream>>>(x, W1, b1, hbuf);
  gemm2_kernel<<<dim3((M / BM) * (N / BN)), dim3(512), 0, stream>>>(hbuf, w21t, b21, W31, part);
  final_kernel<<<dim3(M / 256), dim3(256), 0, stream>>>(part, b31, omean, ostd,
                                                        s0, s1, s2, s3, out);
}